// Round 2
// baseline (875.298 us; speedup 1.0000x reference)
//
#include <hip/hip_runtime.h>
#include <float.h>

// APoT quantizer forward: out = a * nearest_level(clip(x/a, -1, 1))
// a = |alpha| + 1e-8. Nearest per reference semantics:
//   ir = clip(searchsorted(levels, xn, 'left'), 0, L-1); il = clip(ir-1, 0, L-1)
//   choose right iff |xn - left| > |right - xn|  (tie -> left)
// Bit-exact float32 replication (IEEE div, same subs/cmps) => absmax ~ 0.
//
// L = 511 = 2^9 - 1: perfect Eytzinger tree in LDS, 9 ds_read_b32 per element.
// Neighbors (left = last go-right value, right = last go-left value) tracked
// in registers during descent -> no trailing LDS reads. Pads (rank >= L) are
// +FLT_MAX; rank==L case degenerates to choosing levels[L-1], matching ref.

#define TREE_H 9
#define NNODES (1 << TREE_H)   // 512; nodes 1..511 used

typedef float floatx4 __attribute__((ext_vector_type(4)));  // native vec for nontemporal builtins

__device__ __forceinline__ float apot_one(float xi, float a,
                                          const float* __restrict__ eyt,
                                          float lev0, float levmax) {
    float xn = xi / a;                       // IEEE-correct, matches numpy
    xn = fminf(fmaxf(xn, -1.0f), 1.0f);
    int idx = 1;
    float lft = lev0;    // value at il when rank==0
    float rgt = levmax;  // value at ir when rank==L (unreachable after clip, but safe)
    #pragma unroll
    for (int s = 0; s < TREE_H; ++s) {
        float e = eyt[idx];
        bool go_r = e < xn;                  // strict: searchsorted side='left'
        lft = go_r ? e : lft;                // last value we passed going right
        rgt = go_r ? rgt : e;                // last value we passed going left
        idx = 2 * idx + (go_r ? 1 : 0);
    }
    float d_l = fabsf(xn - lft);
    float d_r = fabsf(rgt - xn);
    return a * ((d_l > d_r) ? rgt : lft);    // tie -> left, exactly as reference
}

__global__ __launch_bounds__(256) void apot_kernel(
    const float* __restrict__ x,
    const float* __restrict__ alpha,
    const float* __restrict__ levels,
    float* __restrict__ out,
    long long n, long long n4, int L)
{
    __shared__ float eyt[NNODES];            // eyt[0] unused
    for (int i = threadIdx.x + 1; i < NNODES; i += blockDim.x) {
        int d = 31 - __clz(i);               // depth 0..8
        int pos = i - (1 << d);
        int srt = pos * (1 << (TREE_H - d)) + (1 << (TREE_H - 1 - d)) - 1;
        eyt[i] = (srt < L) ? levels[srt] : FLT_MAX;
    }
    __syncthreads();

    float a = fabsf(alpha[0]) + 1e-8f;
    float lev0 = levels[0];
    float levmax = levels[L - 1];

    long long tid = (long long)blockIdx.x * blockDim.x + threadIdx.x;
    long long stride = (long long)gridDim.x * blockDim.x;

    const floatx4* __restrict__ x4 = (const floatx4*)x;
    floatx4* __restrict__ o4 = (floatx4*)out;
    for (long long t = tid; t < n4; t += stride) {
        floatx4 v = x4[t];
        floatx4 ov;
        ov.x = apot_one(v.x, a, eyt, lev0, levmax);
        ov.y = apot_one(v.y, a, eyt, lev0, levmax);
        ov.z = apot_one(v.z, a, eyt, lev0, levmax);
        ov.w = apot_one(v.w, a, eyt, lev0, levmax);
        __builtin_nontemporal_store(ov, &o4[t]);
    }
    // scalar tail (n not multiple of 4) — empty for this shape, kept for safety
    for (long long t = n4 * 4 + tid; t < n; t += stride) {
        out[t] = apot_one(x[t], a, eyt, lev0, levmax);
    }
}

extern "C" void kernel_launch(void* const* d_in, const int* in_sizes, int n_in,
                              void* d_out, int out_size, void* d_ws, size_t ws_size,
                              hipStream_t stream) {
    const float* x      = (const float*)d_in[0];
    const float* alpha  = (const float*)d_in[1];
    const float* levels = (const float*)d_in[2];
    float* out = (float*)d_out;

    long long n  = (long long)out_size;
    long long n4 = n >> 2;
    int L = in_sizes[2];

    const int block = 256;
    long long want = (n4 + block - 1) / block;
    if (want < 1) want = 1;
    int grid = (int)(want < 8192 ? want : 8192);

    apot_kernel<<<grid, block, 0, stream>>>(x, alpha, levels, out, n, n4, L);
}